// Round 3
// baseline (399.800 us; speedup 1.0000x reference)
//
#include <hip/hip_runtime.h>
#include <hip/hip_bf16.h>
#include <cstdint>

#define HID 64
#define NHEADS 4
#define NEG_SLOPE 0.2f

// ---------------- CSR build ----------------
__global__ void histo_kernel(const int* __restrict__ dst, int* __restrict__ counts, int E) {
    int i = blockIdx.x * blockDim.x + threadIdx.x;
    if (i < E) atomicAdd(&counts[dst[i]], 1);
}

// single-block chunked exclusive scan over n counters -> offs[n+1], wp[n]
__global__ void scan_kernel(const int* __restrict__ counts, int* __restrict__ offs,
                            int* __restrict__ wp, int n) {
    __shared__ int partial[256];
    const int t = threadIdx.x;
    const int chunk = (n + 255) / 256;
    const int lo = t * chunk;
    const int hi = min(lo + chunk, n);
    int s = 0;
    for (int i = lo; i < hi; ++i) s += counts[i];
    partial[t] = s;
    __syncthreads();
    for (int o = 1; o < 256; o <<= 1) {
        int v = (t >= o) ? partial[t - o] : 0;
        __syncthreads();
        partial[t] += v;
        __syncthreads();
    }
    int run = partial[t] - s;  // exclusive prefix of this thread's chunk
    for (int i = lo; i < hi; ++i) {
        offs[i] = run;
        wp[i] = run;
        run += counts[i];
    }
    if (t == 255) offs[n] = partial[255];
}

__global__ void scatter_kernel(const int* __restrict__ src, const int* __restrict__ dst,
                               int* __restrict__ wp, int* __restrict__ csr, int E) {
    int i = blockIdx.x * blockDim.x + threadIdx.x;
    if (i < E) {
        int d = dst[i];
        int p = atomicAdd(&wp[d], 1);
        csr[p] = src[i];
    }
}

// ---------------- GEMM: H[nrows,OUTC] = X[nrows,K] @ W[K,OUTC] ----------------
// BM x BN block tile, 8x8 per thread (64 FMA per 4 ds_read_b128), K staged in
// 32-chunks, both LDS tiles k-major.
template <int K, int OUTC, int BM, int BN>
__global__ __launch_bounds__((BM / 8) * (BN / 8)) void gemm8_kernel(const float* __restrict__ X,
                                                                    const float* __restrict__ W,
                                                                    float* __restrict__ H,
                                                                    int nrows) {
    constexpr int KS = 32;
    constexpr int CG = BN / 8;
    constexpr int THREADS = (BM / 8) * (BN / 8);
    __shared__ float xsT[KS][BM];  // xsT[k][r] = X[row0+r][k0+k]
    __shared__ float wsT[KS][BN];  // wsT[k][c] = W[k0+k][c0+c]
    const int tid = threadIdx.x;
    const int tx = tid % CG;
    const int ty = tid / CG;
    const int row0 = blockIdx.x * BM;
    const int c0 = blockIdx.y * BN;

    float acc[8][8];
#pragma unroll
    for (int i = 0; i < 8; ++i)
#pragma unroll
        for (int j = 0; j < 8; ++j) acc[i][j] = 0.f;

    constexpr int XJ = (KS * BM) / (4 * THREADS);  // float4s of X per thread
    constexpr int WJ = (KS * BN) / (4 * THREADS);  // float4s of W per thread
    const int xr = tid % BM;
    const int xkb = (tid / BM) * (4 * XJ);
    const int xrow = row0 + xr;
    const bool xok = xrow < nrows;

    for (int k0 = 0; k0 < K; k0 += KS) {
        __syncthreads();
        // stage X transposed: lane=row -> conflict-free scalar LDS writes
#pragma unroll
        for (int j = 0; j < XJ; ++j) {
            const int k = xkb + j * 4;
            float4 v = make_float4(0.f, 0.f, 0.f, 0.f);
            if (xok) v = *reinterpret_cast<const float4*>(&X[(size_t)xrow * K + k0 + k]);
            xsT[k + 0][xr] = v.x;
            xsT[k + 1][xr] = v.y;
            xsT[k + 2][xr] = v.z;
            xsT[k + 3][xr] = v.w;
        }
        // stage W (already k-major): contiguous float4 copies
#pragma unroll
        for (int j = 0; j < WJ; ++j) {
            const int fi = tid + j * THREADS;
            const int k = fi / (BN / 4);
            const int c = (fi % (BN / 4)) * 4;
            float4 v = *reinterpret_cast<const float4*>(&W[(size_t)(k0 + k) * OUTC + c0 + c]);
            *reinterpret_cast<float4*>(&wsT[k][c]) = v;
        }
        __syncthreads();
#pragma unroll 4
        for (int k = 0; k < KS; ++k) {
            const float4 a0 = *reinterpret_cast<const float4*>(&xsT[k][ty * 8]);
            const float4 a1 = *reinterpret_cast<const float4*>(&xsT[k][ty * 8 + 4]);
            const float4 b0 = *reinterpret_cast<const float4*>(&wsT[k][tx * 8]);
            const float4 b1 = *reinterpret_cast<const float4*>(&wsT[k][tx * 8 + 4]);
            const float av[8] = {a0.x, a0.y, a0.z, a0.w, a1.x, a1.y, a1.z, a1.w};
            const float bv[8] = {b0.x, b0.y, b0.z, b0.w, b1.x, b1.y, b1.z, b1.w};
#pragma unroll
            for (int i = 0; i < 8; ++i)
#pragma unroll
                for (int j = 0; j < 8; ++j) acc[i][j] = fmaf(av[i], bv[j], acc[i][j]);
        }
    }
#pragma unroll
    for (int i = 0; i < 8; ++i) {
        const int row = row0 + ty * 8 + i;
        if (row < nrows) {
            float4 v0 = make_float4(acc[i][0], acc[i][1], acc[i][2], acc[i][3]);
            float4 v1 = make_float4(acc[i][4], acc[i][5], acc[i][6], acc[i][7]);
            *reinterpret_cast<float4*>(&H[(size_t)row * OUTC + c0 + tx * 8]) = v0;
            *reinterpret_cast<float4*>(&H[(size_t)row * OUTC + c0 + tx * 8 + 4]) = v1;
        }
    }
}

// ---------------- per-node attention logits ----------------
__global__ void alpha_kernel(const float* __restrict__ h, const float* __restrict__ a_s,
                             const float* __restrict__ a_d, float* __restrict__ alpha_s,
                             float* __restrict__ alpha_d, int n_nodes, int heads) {
    const int gw = (blockIdx.x * blockDim.x + threadIdx.x) >> 6;
    const int lane = threadIdx.x & 63;
    const int total = n_nodes * heads;
    if (gw >= total) return;
    const int n = gw / heads;
    const int hd = gw - n * heads;
    const float v = h[(size_t)n * heads * 64 + hd * 64 + lane];
    float vs = v * a_s[hd * 64 + lane];
    float vd = v * a_d[hd * 64 + lane];
#pragma unroll
    for (int o = 32; o; o >>= 1) {
        vs += __shfl_xor(vs, o);
        vd += __shfl_xor(vd, o);
    }
    if (lane == 0) {
        alpha_s[gw] = vs;
        alpha_d[gw] = vd;
    }
}

__device__ __forceinline__ float leaky(float e) {
    return (e > 0.f) ? e : NEG_SLOPE * e;
}

// ---------------- segment softmax -> per-edge weights (CSR order) ----------------
// one wave per node; lanes stride the node's edge list
template <int H>
__global__ __launch_bounds__(256) void maxsumw_kernel(const float* __restrict__ alpha_s,
                                                      const float* __restrict__ alpha_d,
                                                      const int* __restrict__ offs,
                                                      const int* __restrict__ csr,
                                                      float* __restrict__ w, int n_nodes) {
    const int n = (blockIdx.x * blockDim.x + threadIdx.x) >> 6;
    const int lane = threadIdx.x & 63;
    if (n >= n_nodes) return;
    const int start = offs[n];
    const int end = offs[n + 1];

    float ad[H], m[H], sum[H];
#pragma unroll
    for (int h = 0; h < H; ++h) {
        ad[h] = alpha_d[n * H + h];
        m[h] = -INFINITY;
        sum[h] = 0.f;
    }
    // pass 1: max
    for (int i = start + lane; i < end; i += 64) {
        const int s = csr[i];
#pragma unroll
        for (int h = 0; h < H; ++h) m[h] = fmaxf(m[h], leaky(alpha_s[s * H + h] + ad[h]));
    }
#pragma unroll
    for (int o = 32; o; o >>= 1)
#pragma unroll
        for (int h = 0; h < H; ++h) m[h] = fmaxf(m[h], __shfl_xor(m[h], o));
    // pass 2: exp + sum, store raw ex
    for (int i = start + lane; i < end; i += 64) {
        const int s = csr[i];
        float ex[H];
#pragma unroll
        for (int h = 0; h < H; ++h) {
            ex[h] = __expf(leaky(alpha_s[s * H + h] + ad[h]) - m[h]);
            sum[h] += ex[h];
        }
        if (H == 4) {
            float4 v = make_float4(ex[0], ex[1], ex[2], ex[3]);
            *reinterpret_cast<float4*>(&w[(size_t)i * 4]) = v;
        } else {
            w[i] = ex[0];
        }
    }
#pragma unroll
    for (int o = 32; o; o >>= 1)
#pragma unroll
        for (int h = 0; h < H; ++h) sum[h] += __shfl_xor(sum[h], o);
    float recip[H];
#pragma unroll
    for (int h = 0; h < H; ++h) recip[h] = 1.f / (sum[h] + 1e-16f);
    // pass 3: normalize
    for (int i = start + lane; i < end; i += 64) {
        if (H == 4) {
            float4 v = *reinterpret_cast<float4*>(&w[(size_t)i * 4]);
            v.x *= recip[0];
            v.y *= recip[1];
            v.z *= recip[2];
            v.w *= recip[3];
            *reinterpret_cast<float4*>(&w[(size_t)i * 4]) = v;
        } else {
            w[i] *= recip[0];
        }
    }
}

// ---------------- aggregation: weighted gather-sum ----------------
// one wave per (node, head); lane = channel; weights precomputed
template <int H, bool RELU>
__global__ __launch_bounds__(256) void agg2_kernel(const float* __restrict__ h,
                                                   const float* __restrict__ w,
                                                   const int* __restrict__ offs,
                                                   const int* __restrict__ csr,
                                                   const float* __restrict__ bias,
                                                   float* __restrict__ out, int n_nodes) {
    int n, hd;
    if (H == 4) {
        n = blockIdx.x;
        hd = threadIdx.x >> 6;
    } else {
        n = blockIdx.x * 4 + (threadIdx.x >> 6);
        hd = 0;
    }
    const int c = threadIdx.x & 63;
    if (n >= n_nodes) return;
    const int start = offs[n];
    const int end = offs[n + 1];

    float acc0 = 0.f, acc1 = 0.f;
    int i = start;
    for (; i + 1 < end; i += 2) {
        const int s0 = csr[i];
        const int s1 = csr[i + 1];
        const float w0 = w[(size_t)i * H + hd];
        const float w1 = w[(size_t)(i + 1) * H + hd];
        acc0 = fmaf(w0, h[(size_t)s0 * (H * 64) + hd * 64 + c], acc0);
        acc1 = fmaf(w1, h[(size_t)s1 * (H * 64) + hd * 64 + c], acc1);
    }
    if (i < end) {
        const int s0 = csr[i];
        const float w0 = w[(size_t)i * H + hd];
        acc0 = fmaf(w0, h[(size_t)s0 * (H * 64) + hd * 64 + c], acc0);
    }
    float o = acc0 + acc1 + bias[hd * 64 + c];
    if (RELU) o = fmaxf(o, 0.f);
    out[(size_t)n * (H * 64) + hd * 64 + c] = o;
}

// ---------------- launch ----------------
extern "C" void kernel_launch(void* const* d_in, const int* in_sizes, int n_in,
                              void* d_out, int out_size, void* d_ws, size_t ws_size,
                              hipStream_t stream) {
    const float* x   = (const float*)d_in[0];
    const int*   ei  = (const int*)d_in[1];
    const float* W1  = (const float*)d_in[2];
    const float* a1s = (const float*)d_in[3];
    const float* a1d = (const float*)d_in[4];
    const float* b1  = (const float*)d_in[5];
    const float* W2  = (const float*)d_in[6];
    const float* a2s = (const float*)d_in[7];
    const float* a2d = (const float*)d_in[8];
    const float* b2  = (const float*)d_in[9];
    const float* W3  = (const float*)d_in[10];
    const float* a3s = (const float*)d_in[11];
    const float* a3d = (const float*)d_in[12];
    const float* b3  = (const float*)d_in[13];
    float* out = (float*)d_out;

    const int N = in_sizes[0] / HID;
    const int E = in_sizes[1] / 2;
    const int* src = ei;
    const int* dst = ei + E;

    char* p = (char*)d_ws;
    auto alloc = [&](size_t bytes) {
        char* q = p;
        p += (bytes + 255) & ~(size_t)255;
        return q;
    };
    float* bufA = (float*)alloc((size_t)N * 256 * 4);
    float* bufB = (float*)alloc((size_t)N * 256 * 4);
    float* alpS = (float*)alloc((size_t)N * NHEADS * 4);
    float* alpD = (float*)alloc((size_t)N * NHEADS * 4);
    float* wbuf = (float*)alloc((size_t)E * NHEADS * 4);
    int* counts = (int*)alloc((size_t)N * 4);
    int* offs   = (int*)alloc((size_t)(N + 1) * 4);
    int* wp     = (int*)alloc((size_t)N * 4);
    int* csr    = (int*)alloc((size_t)E * 4);

    hipMemsetAsync(counts, 0, (size_t)N * 4, stream);
    const int eb = (E + 255) / 256;
    histo_kernel<<<eb, 256, 0, stream>>>(dst, counts, E);
    scan_kernel<<<1, 256, 0, stream>>>(counts, offs, wp, N);
    scatter_kernel<<<eb, 256, 0, stream>>>(src, dst, wp, csr, E);

    const int gb64 = (N + 63) / 64;
    const int nwb = (N * 64 + 255) / 256;  // maxsumw: wave per node

    // layer 1: x[N,64] @ W1[64,256]
    gemm8_kernel<64, 256, 64, 128><<<dim3(gb64, 2), 128, 0, stream>>>(x, W1, bufA, N);
    alpha_kernel<<<(N * NHEADS * 64 + 255) / 256, 256, 0, stream>>>(bufA, a1s, a1d, alpS, alpD, N, NHEADS);
    maxsumw_kernel<NHEADS><<<nwb, 256, 0, stream>>>(alpS, alpD, offs, csr, wbuf, N);
    agg2_kernel<NHEADS, true><<<N, 256, 0, stream>>>(bufA, wbuf, offs, csr, b1, bufB, N);

    // layer 2: bufB[N,256] @ W2[256,256]
    gemm8_kernel<256, 256, 64, 128><<<dim3(gb64, 2), 128, 0, stream>>>(bufB, W2, bufA, N);
    alpha_kernel<<<(N * NHEADS * 64 + 255) / 256, 256, 0, stream>>>(bufA, a2s, a2d, alpS, alpD, N, NHEADS);
    maxsumw_kernel<NHEADS><<<nwb, 256, 0, stream>>>(alpS, alpD, offs, csr, wbuf, N);
    agg2_kernel<NHEADS, true><<<N, 256, 0, stream>>>(bufA, wbuf, offs, csr, b2, bufB, N);

    // layer 3: bufB[N,256] @ W3[256,64], 1 head, no relu
    gemm8_kernel<256, 64, 64, 64><<<dim3(gb64, 1), 64, 0, stream>>>(bufB, W3, bufA, N);
    alpha_kernel<<<(N * 1 * 64 + 255) / 256, 256, 0, stream>>>(bufA, a3s, a3d, alpS, alpD, N, 1);
    maxsumw_kernel<1><<<nwb, 256, 0, stream>>>(alpS, alpD, offs, csr, wbuf, N);
    agg2_kernel<1, false><<<(N + 3) / 4, 256, 0, stream>>>(bufA, wbuf, offs, csr, b3, out, N);
}